// Round 4
// baseline (86.905 us; speedup 1.0000x reference)
//
#include <hip/hip_runtime.h>

typedef float v2f __attribute__((ext_vector_type(2)));

constexpr int NQ = 4;
constexpr int DIM = 16;          // 2^NQ
constexpr float MARGIN = 0.3f;
constexpr float INV2PI = 0.15915494309189535f;

__device__ __forceinline__ v2f mk2(float x, float y) { v2f r; r.x = x; r.y = y; return r; }

// complex multiply a*b where bs = {-b.y, b.x} is precomputed.
__device__ __forceinline__ v2f cmul_pre(v2f a, v2f b, v2f bs) {
  return a.xx * b + a.yy * bs;
}

__device__ __forceinline__ void sincos_hw(float rev, float& s, float& c) {
  s = __builtin_amdgcn_sinf(rev);   // input in revolutions
  c = __builtin_amdgcn_cosf(rev);
}

// CNOT ladder CNOT(q,q+1), q=0..2; qubit q == flat bit (3-q). Free permutation.
__device__ __forceinline__ void cnot_ladder(v2f s[DIM]) {
#pragma unroll
  for (int q = 0; q < NQ - 1; ++q) {
    const int pc = 1 << (NQ - 1 - q);
    const int pt = 1 << (NQ - 2 - q);
#pragma unroll
    for (int i = 0; i < DIM; ++i) {
      if ((i & pc) && !(i & pt)) {
        const int j = i | pt;
        v2f t = s[i]; s[i] = s[j]; s[j] = t;
      }
    }
  }
}

// Layer-1 product state (RZ as diag(1,e^{i z}), global phase dropped) + CNOT ladder.
__device__ __forceinline__ void layer1_cl(const float ry[8], const float rz[8], v2f s[DIM]) {
  float c0[NQ]; v2f p1[NQ], p1s[NQ];
#pragma unroll
  for (int q = 0; q < NQ; ++q) {
    float sy, cy; sincos_hw(ry[q] * (0.5f * INV2PI), sy, cy);
    float sz, cz; sincos_hw(rz[q] * INV2PI, sz, cz);
    c0[q]  = cy;
    p1[q]  = mk2(sy * cz, sy * sz);
    p1s[q] = mk2(-p1[q].y, p1[q].x);
  }
  v2f t2[4];
  t2[0] = mk2(c0[0] * c0[1], 0.0f);
  t2[1] = c0[0] * p1[1];
  t2[2] = c0[1] * p1[0];
  t2[3] = cmul_pre(p1[0], p1[1], p1s[1]);
  v2f t3[8];
#pragma unroll
  for (int k = 0; k < 4; ++k) {
    t3[2*k]   = t2[k] * c0[2];
    t3[2*k+1] = cmul_pre(t2[k], p1[2], p1s[2]);
  }
#pragma unroll
  for (int k = 0; k < 8; ++k) {
    s[2*k]   = t3[k] * c0[3];
    s[2*k+1] = cmul_pre(t3[k], p1[3], p1s[3]);
  }
  cnot_ladder(s);
}

// One RY butterfly layer (angles ry[4..7]).
__device__ __forceinline__ void ry_layer(const float ry[8], v2f s[DIM]) {
#pragma unroll
  for (int q = 0; q < NQ; ++q) {
    const int bit = 1 << (NQ - 1 - q);
    float sy, cy; sincos_hw(ry[4 + q] * (0.5f * INV2PI), sy, cy);
#pragma unroll
    for (int i = 0; i < DIM; ++i) {
      if (i & bit) continue;
      const int j = i | bit;
      const v2f a0 = s[i], a1 = s[j];
      s[i] = cy * a0 - sy * a1;
      s[j] = sy * a0 + cy * a1;
    }
  }
}

__device__ __forceinline__ void load8(const float* __restrict__ p, int b, float a[8]) {
  const float4* v = reinterpret_cast<const float4*>(p) + (size_t)b * 2;
  float4 x0 = v[0], x1 = v[1];
  a[0]=x0.x; a[1]=x0.y; a[2]=x0.z; a[3]=x0.w;
  a[4]=x1.x; a[5]=x1.y; a[6]=x1.z; a[7]=x1.w;
}

__global__ __launch_bounds__(256) void triplet_fused(
    const float* __restrict__ a_ry, const float* __restrict__ a_rz,
    const float* __restrict__ p_ry, const float* __restrict__ p_rz,
    const float* __restrict__ n_ry, const float* __restrict__ n_rz,
    float* __restrict__ partials, unsigned* __restrict__ counter,
    float* __restrict__ out, int batch) {
  const int b = blockIdx.x * blockDim.x + threadIdx.x;

  float loss = 0.0f;
  if (b < batch) {
    // ---- anchor: u_a = RY2( CL( L1 ) )  (final RZ layer merged into the dots) ----
    float ary[8], arz[8];
    load8(a_ry, b, ary); load8(a_rz, b, arz);
    v2f as[DIM];
    layer1_cl(ary, arz, as);
    ry_layer(ary, as);

    // ---- positive & negative, explicitly interleaved (independent chains) ----
    float pry[8], prz[8], nry[8], nrz[8];
    load8(p_ry, b, pry); load8(p_rz, b, prz);
    load8(n_ry, b, nry); load8(n_rz, b, nrz);

    v2f xs[DIM], ys[DIM];
    layer1_cl(pry, prz, xs);
    layer1_cl(nry, nrz, ys);

    // interleaved RY layer 2
#pragma unroll
    for (int q = 0; q < NQ; ++q) {
      const int bit = 1 << (NQ - 1 - q);
      float syp, cyp; sincos_hw(pry[4 + q] * (0.5f * INV2PI), syp, cyp);
      float syn, cyn; sincos_hw(nry[4 + q] * (0.5f * INV2PI), syn, cyn);
#pragma unroll
      for (int i = 0; i < DIM; ++i) {
        if (i & bit) continue;
        const int j = i | bit;
        const v2f x0 = xs[i], x1 = xs[j];
        xs[i] = cyp * x0 - syp * x1;
        xs[j] = syp * x0 + cyp * x1;
        const v2f y0 = ys[i], y1 = ys[j];
        ys[i] = cyn * y0 - syn * y1;
        ys[j] = syn * y0 + cyn * y1;
      }
    }

    // merged final RZ: apply diag(1, e^{i(z - za)}) per qubit (anchor RZ folded in)
#pragma unroll
    for (int q = 0; q < NQ; ++q) {
      const int bit = 1 << (NQ - 1 - q);
      float szp, czp; sincos_hw((prz[4 + q] - arz[4 + q]) * INV2PI, szp, czp);
      float szn, czn; sincos_hw((nrz[4 + q] - arz[4 + q]) * INV2PI, szn, czn);
      const v2f php  = mk2(czp, szp), phps = mk2(-szp, czp);
      const v2f phn  = mk2(czn, szn), phns = mk2(-szn, czn);
#pragma unroll
      for (int i = 0; i < DIM; ++i) {
        if (i & bit) {
          xs[i] = cmul_pre(xs[i], php, phps);
          ys[i] = cmul_pre(ys[i], phn, phns);
        }
      }
    }

    // interleaved overlap dots (4 independent accumulator chains)
    v2f op1 = mk2(0.f,0.f), op2 = mk2(0.f,0.f);
    v2f on1 = mk2(0.f,0.f), on2 = mk2(0.f,0.f);
#pragma unroll
    for (int i = 0; i < DIM; ++i) {
      op1 += as[i].xx * xs[i];
      op2 += as[i].yy * xs[i].yx;
      on1 += as[i].xx * ys[i];
      on2 += as[i].yy * ys[i].yx;
    }
    const float opr = op1.x + op2.x, opi = op1.y - op2.y;
    const float onr = on1.x + on2.x, oni = on1.y - on2.y;
    const float fid_pos = opr*opr + opi*opi;
    const float fid_neg = onr*onr + oni*oni;

    loss = fmaxf(MARGIN - fid_pos + fid_neg, 0.0f);
  }

  // wave (64) reduce, then LDS across the 4 waves
#pragma unroll
  for (int off = 32; off >= 1; off >>= 1)
    loss += __shfl_down(loss, off, 64);

  __shared__ float wsum[4];
  const int lane = threadIdx.x & 63;
  const int wid  = threadIdx.x >> 6;
  if (lane == 0) wsum[wid] = loss;
  __syncthreads();

  __shared__ bool amLast;
  if (threadIdx.x == 0) {
    partials[blockIdx.x] = wsum[0] + wsum[1] + wsum[2] + wsum[3];
    __threadfence();                        // release partial
    unsigned old = atomicAdd(counter, 1u);  // device-scope
    amLast = (old == gridDim.x - 1);
  }
  __syncthreads();

  if (amLast) {
    __threadfence();                        // acquire all partials
    float s = 0.0f;
    for (int i = threadIdx.x; i < (int)gridDim.x; i += 256) s += partials[i];
#pragma unroll
    for (int off = 32; off >= 1; off >>= 1)
      s += __shfl_down(s, off, 64);
    if (lane == 0) wsum[wid] = s;
    __syncthreads();
    if (threadIdx.x == 0)
      out[0] = (wsum[0] + wsum[1] + wsum[2] + wsum[3]) / (float)batch;
  }
}

extern "C" void kernel_launch(void* const* d_in, const int* in_sizes, int n_in,
                              void* d_out, int out_size, void* d_ws, size_t ws_size,
                              hipStream_t stream) {
  const float* a_ry = (const float*)d_in[0];
  const float* a_rz = (const float*)d_in[1];
  const float* p_ry = (const float*)d_in[2];
  const float* p_rz = (const float*)d_in[3];
  const float* n_ry = (const float*)d_in[4];
  const float* n_rz = (const float*)d_in[5];
  float* out = (float*)d_out;

  const int batch = in_sizes[0] / 8;            // NL*NQ = 8 angles per element
  const int nblocks = (batch + 255) / 256;      // 2048

  float* partials = (float*)d_ws;
  unsigned* counter = (unsigned*)((char*)d_ws + (size_t)nblocks * sizeof(float));

  hipMemsetAsync(counter, 0, sizeof(unsigned), stream);  // captured into the graph

  triplet_fused<<<nblocks, 256, 0, stream>>>(a_ry, a_rz, p_ry, p_rz, n_ry, n_rz,
                                             partials, counter, out, batch);
}